// Round 1
// baseline (4129.177 us; speedup 1.0000x reference)
//
#include <hip/hip_runtime.h>
#include <hip/hip_bf16.h>
#include <stddef.h>

#define DM    512
#define NHEAD 8
#define DHEAD 64
#define QLEN  1024
#define KLEN  2048
#define MLEN  1024
#define B_SZ  4
#define BQ    4

// ---------------------------------------------------------------------------
// C[M][512] = A'[M][512] * W[512][512]   (W row-major, contraction over rows)
// A' row m maps to A row: (m / rpbOut)*rpbIn + (m % rpbOut) + rowOff
// ---------------------------------------------------------------------------
__global__ __launch_bounds__(256) void k_gemm_proj(
    const float* __restrict__ A, const float* __restrict__ W,
    float* __restrict__ C, int rpbOut, int rpbIn, int rowOff) {
  __shared__ alignas(16) float As[16][64];
  __shared__ alignas(16) float Bs[16][64];
  const int tid = threadIdx.x;
  const int bm = blockIdx.x, bn = blockIdx.y;
  const int tx = tid & 15, ty = tid >> 4;
  const int arow = tid >> 2;
  const int acol = (tid & 3) << 2;
  const int brow = tid >> 4;
  const int bcol = (tid & 15) << 2;
  const int m = bm * 64 + arow;
  const size_t gr = (size_t)(m / rpbOut) * rpbIn + (m % rpbOut) + rowOff;
  const float* Arow = A + gr * DM;
  float acc[4][4] = {};
  for (int k0 = 0; k0 < DM; k0 += 16) {
    float4 a4 = *(const float4*)(Arow + k0 + acol);
    As[acol + 0][arow] = a4.x;
    As[acol + 1][arow] = a4.y;
    As[acol + 2][arow] = a4.z;
    As[acol + 3][arow] = a4.w;
    *(float4*)&Bs[brow][bcol] =
        *(const float4*)(W + (size_t)(k0 + brow) * DM + bn * 64 + bcol);
    __syncthreads();
#pragma unroll
    for (int kk = 0; kk < 16; ++kk) {
      float4 a = *(const float4*)&As[kk][ty << 2];
      float4 b = *(const float4*)&Bs[kk][tx << 2];
      acc[0][0] = fmaf(a.x, b.x, acc[0][0]);
      acc[0][1] = fmaf(a.x, b.y, acc[0][1]);
      acc[0][2] = fmaf(a.x, b.z, acc[0][2]);
      acc[0][3] = fmaf(a.x, b.w, acc[0][3]);
      acc[1][0] = fmaf(a.y, b.x, acc[1][0]);
      acc[1][1] = fmaf(a.y, b.y, acc[1][1]);
      acc[1][2] = fmaf(a.y, b.z, acc[1][2]);
      acc[1][3] = fmaf(a.y, b.w, acc[1][3]);
      acc[2][0] = fmaf(a.z, b.x, acc[2][0]);
      acc[2][1] = fmaf(a.z, b.y, acc[2][1]);
      acc[2][2] = fmaf(a.z, b.z, acc[2][2]);
      acc[2][3] = fmaf(a.z, b.w, acc[2][3]);
      acc[3][0] = fmaf(a.w, b.x, acc[3][0]);
      acc[3][1] = fmaf(a.w, b.y, acc[3][1]);
      acc[3][2] = fmaf(a.w, b.z, acc[3][2]);
      acc[3][3] = fmaf(a.w, b.w, acc[3][3]);
    }
    __syncthreads();
  }
  float* Crow = C + (size_t)(bm * 64 + (ty << 2)) * DM + bn * 64 + (tx << 2);
#pragma unroll
  for (int i = 0; i < 4; ++i) {
    float4 o;
    o.x = acc[i][0]; o.y = acc[i][1]; o.z = acc[i][2]; o.w = acc[i][3];
    *(float4*)(Crow + (size_t)i * DM) = o;
  }
}

// ---------------------------------------------------------------------------
// C[4096][512] = A[4096][512] * Wo[512][512]^T  (contraction over Wo's cols)
// ---------------------------------------------------------------------------
__global__ __launch_bounds__(256) void k_gemm_out(
    const float* __restrict__ A, const float* __restrict__ W,
    float* __restrict__ C) {
  __shared__ alignas(16) float As[16][64];
  __shared__ alignas(16) float Bs[16][64];
  const int tid = threadIdx.x;
  const int bm = blockIdx.x, bn = blockIdx.y;
  const int tx = tid & 15, ty = tid >> 4;
  const int arow = tid >> 2;
  const int acol = (tid & 3) << 2;
  const int wrow = tid >> 2;            // output-col index within tile
  const int wcol = (tid & 3) << 2;      // k within tile
  const float* Arow = A + (size_t)(bm * 64 + arow) * DM;
  float acc[4][4] = {};
  for (int k0 = 0; k0 < DM; k0 += 16) {
    float4 a4 = *(const float4*)(Arow + k0 + acol);
    As[acol + 0][arow] = a4.x;
    As[acol + 1][arow] = a4.y;
    As[acol + 2][arow] = a4.z;
    As[acol + 3][arow] = a4.w;
    float4 w4 = *(const float4*)(W + (size_t)(bn * 64 + wrow) * DM + k0 + wcol);
    Bs[wcol + 0][wrow] = w4.x;
    Bs[wcol + 1][wrow] = w4.y;
    Bs[wcol + 2][wrow] = w4.z;
    Bs[wcol + 3][wrow] = w4.w;
    __syncthreads();
#pragma unroll
    for (int kk = 0; kk < 16; ++kk) {
      float4 a = *(const float4*)&As[kk][ty << 2];
      float4 b = *(const float4*)&Bs[kk][tx << 2];
      acc[0][0] = fmaf(a.x, b.x, acc[0][0]);
      acc[0][1] = fmaf(a.x, b.y, acc[0][1]);
      acc[0][2] = fmaf(a.x, b.z, acc[0][2]);
      acc[0][3] = fmaf(a.x, b.w, acc[0][3]);
      acc[1][0] = fmaf(a.y, b.x, acc[1][0]);
      acc[1][1] = fmaf(a.y, b.y, acc[1][1]);
      acc[1][2] = fmaf(a.y, b.z, acc[1][2]);
      acc[1][3] = fmaf(a.y, b.w, acc[1][3]);
      acc[2][0] = fmaf(a.z, b.x, acc[2][0]);
      acc[2][1] = fmaf(a.z, b.y, acc[2][1]);
      acc[2][2] = fmaf(a.z, b.z, acc[2][2]);
      acc[2][3] = fmaf(a.z, b.w, acc[2][3]);
      acc[3][0] = fmaf(a.w, b.x, acc[3][0]);
      acc[3][1] = fmaf(a.w, b.y, acc[3][1]);
      acc[3][2] = fmaf(a.w, b.z, acc[3][2]);
      acc[3][3] = fmaf(a.w, b.w, acc[3][3]);
    }
    __syncthreads();
  }
  float* Crow = C + (size_t)(bm * 64 + (ty << 2)) * DM + bn * 64 + (tx << 2);
#pragma unroll
  for (int i = 0; i < 4; ++i) {
    float4 o;
    o.x = acc[i][0]; o.y = acc[i][1]; o.z = acc[i][2]; o.w = acc[i][3];
    *(float4*)(Crow + (size_t)i * DM) = o;
  }
}

// ---------------------------------------------------------------------------
// Attention: one block per (b, head, 4 query rows).
// score(i,j) = (q_i+bk)·k_j + (q_i+br)·r[j-i+QLEN-1],  valid j <= i+MLEN
// ---------------------------------------------------------------------------
__global__ __launch_bounds__(256) void k_attn(
    const float* __restrict__ q, const float* __restrict__ k,
    const float* __restrict__ v, const float* __restrict__ r,
    const float* __restrict__ bk, const float* __restrict__ br,
    float* __restrict__ ao) {
  __shared__ float s[BQ][KLEN];          // 32 KB (unnormalized probs at end)
  __shared__ float qk[BQ][DHEAD];
  __shared__ float qr[BQ][DHEAD];
  __shared__ float tmpr[BQ][256];
  __shared__ float red[4][BQ][DHEAD];
  const int tid = threadIdx.x;
  const int i0 = blockIdx.x * BQ;
  const int n = blockIdx.y;
  const int b = blockIdx.z;

  for (int t = tid; t < BQ * DHEAD; t += 256) {
    int qi = t >> 6, d = t & 63;
    float qv = q[(size_t)(b * QLEN + i0 + qi) * DM + n * DHEAD + d];
    qk[qi][d] = qv + bk[n * DHEAD + d];
    qr[qi][d] = qv + br[n * DHEAD + d];
  }
  __syncthreads();
  const int jmaxAll = i0 + (BQ - 1) + MLEN + 1;   // exclusive, <= 2048

  // Phase 1a: AC terms
  for (int j = tid; j < jmaxAll; j += 256) {
    const float* krow = k + (size_t)(b * KLEN + j) * DM + n * DHEAD;
    float acc[BQ] = {0.f, 0.f, 0.f, 0.f};
#pragma unroll
    for (int d4 = 0; d4 < DHEAD; d4 += 4) {
      float4 kv = *(const float4*)(krow + d4);
#pragma unroll
      for (int qi = 0; qi < BQ; ++qi) {
        acc[qi] = fmaf(qk[qi][d4 + 0], kv.x, acc[qi]);
        acc[qi] = fmaf(qk[qi][d4 + 1], kv.y, acc[qi]);
        acc[qi] = fmaf(qk[qi][d4 + 2], kv.z, acc[qi]);
        acc[qi] = fmaf(qk[qi][d4 + 3], kv.w, acc[qi]);
      }
    }
#pragma unroll
    for (int qi = 0; qi < BQ; ++qi) s[qi][j] = acc[qi];
  }
  __syncthreads();

  // Phase 1b: BD terms via relative index jr = j - i + (QLEN-1)
  int jrMin = (QLEN - 1) - (i0 + BQ - 1);
  if (jrMin < 0) jrMin = 0;
  for (int jr = jrMin + tid; jr < KLEN; jr += 256) {
    const float* rrow = r + (size_t)jr * DM + n * DHEAD;
    float acc[BQ] = {0.f, 0.f, 0.f, 0.f};
#pragma unroll
    for (int d4 = 0; d4 < DHEAD; d4 += 4) {
      float4 rv = *(const float4*)(rrow + d4);
#pragma unroll
      for (int qi = 0; qi < BQ; ++qi) {
        acc[qi] = fmaf(qr[qi][d4 + 0], rv.x, acc[qi]);
        acc[qi] = fmaf(qr[qi][d4 + 1], rv.y, acc[qi]);
        acc[qi] = fmaf(qr[qi][d4 + 2], rv.z, acc[qi]);
        acc[qi] = fmaf(qr[qi][d4 + 3], rv.w, acc[qi]);
      }
    }
#pragma unroll
    for (int qi = 0; qi < BQ; ++qi) {
      int i = i0 + qi;
      int j = jr + i - (QLEN - 1);
      if (j >= 0 && j <= i + MLEN) s[qi][j] += acc[qi];
    }
  }
  __syncthreads();

  // Phase 2: masked softmax (scale 1/8), leave unnormalized probs in s
  float mx[BQ];
#pragma unroll
  for (int qi = 0; qi < BQ; ++qi) mx[qi] = -3.0e38f;
  for (int j = tid; j < jmaxAll; j += 256) {
#pragma unroll
    for (int qi = 0; qi < BQ; ++qi)
      if (j <= i0 + qi + MLEN) mx[qi] = fmaxf(mx[qi], s[qi][j]);
  }
#pragma unroll
  for (int qi = 0; qi < BQ; ++qi) tmpr[qi][tid] = mx[qi];
  __syncthreads();
  for (int off = 128; off > 0; off >>= 1) {
    if (tid < off) {
#pragma unroll
      for (int qi = 0; qi < BQ; ++qi)
        tmpr[qi][tid] = fmaxf(tmpr[qi][tid], tmpr[qi][tid + off]);
    }
    __syncthreads();
  }
#pragma unroll
  for (int qi = 0; qi < BQ; ++qi) mx[qi] = tmpr[qi][0];
  __syncthreads();
  float sm[BQ] = {0.f, 0.f, 0.f, 0.f};
  for (int j = tid; j < jmaxAll; j += 256) {
#pragma unroll
    for (int qi = 0; qi < BQ; ++qi) {
      float pv = 0.f;
      if (j <= i0 + qi + MLEN) {
        pv = __expf(0.125f * (s[qi][j] - mx[qi]));
        sm[qi] += pv;
      }
      s[qi][j] = pv;
    }
  }
#pragma unroll
  for (int qi = 0; qi < BQ; ++qi) tmpr[qi][tid] = sm[qi];
  __syncthreads();
  for (int off = 128; off > 0; off >>= 1) {
    if (tid < off) {
#pragma unroll
      for (int qi = 0; qi < BQ; ++qi)
        tmpr[qi][tid] += tmpr[qi][tid + off];
    }
    __syncthreads();
  }
  float inv[BQ];
#pragma unroll
  for (int qi = 0; qi < BQ; ++qi) inv[qi] = 1.0f / tmpr[qi][0];

  // Phase 3: PV.  wave w handles j = w mod 4; lane = d.
  const int wave = tid >> 6, lane = tid & 63;
  float acc[BQ] = {0.f, 0.f, 0.f, 0.f};
  for (int j = wave; j < jmaxAll; j += 4) {
    float vv = v[(size_t)(b * KLEN + j) * DM + n * DHEAD + lane];
#pragma unroll
    for (int qi = 0; qi < BQ; ++qi) acc[qi] = fmaf(s[qi][j], vv, acc[qi]);
  }
#pragma unroll
  for (int qi = 0; qi < BQ; ++qi) red[wave][qi][lane] = acc[qi];
  __syncthreads();
  if (tid < BQ * DHEAD) {
    int qi = wave, d = lane;   // tid < 256 always true; qi = tid>>6
    float o = red[0][qi][d] + red[1][qi][d] + red[2][qi][d] + red[3][qi][d];
    float iv = (qi == 0) ? inv[0] : (qi == 1) ? inv[1] : (qi == 2) ? inv[2] : inv[3];
    ao[(size_t)(b * QLEN + i0 + qi) * DM + n * DHEAD + d] = o * iv;
  }
}

// ---------------------------------------------------------------------------
extern "C" void kernel_launch(void* const* d_in, const int* in_sizes, int n_in,
                              void* d_out, int out_size, void* d_ws, size_t ws_size,
                              hipStream_t stream) {
  const float* x  = (const float*)d_in[0];
  const float* p  = (const float*)d_in[1];
  const float* Wq = (const float*)d_in[2];
  const float* Wk = (const float*)d_in[3];
  const float* Wv = (const float*)d_in[4];
  const float* Wo = (const float*)d_in[5];
  const float* Wp = (const float*)d_in[6];
  const float* bk = (const float*)d_in[7];
  const float* br = (const float*)d_in[8];
  float* out = (float*)d_out;

  float* q_ = (float*)d_ws;                               // [4096][512]
  float* k_ = q_ + (size_t)B_SZ * QLEN * DM;              // [8192][512]
  float* v_ = k_ + (size_t)B_SZ * KLEN * DM;              // [8192][512]
  float* r_ = v_ + (size_t)B_SZ * KLEN * DM;              // [2048][512]
  float* ao = r_ + (size_t)KLEN * DM;                     // [4096][512]

  k_gemm_proj<<<dim3(B_SZ * QLEN / 64, DM / 64), 256, 0, stream>>>(
      x, Wq, q_, QLEN, KLEN, MLEN);
  k_gemm_proj<<<dim3(B_SZ * KLEN / 64, DM / 64), 256, 0, stream>>>(
      x, Wk, k_, KLEN, KLEN, 0);
  k_gemm_proj<<<dim3(B_SZ * KLEN / 64, DM / 64), 256, 0, stream>>>(
      x, Wv, v_, KLEN, KLEN, 0);
  k_gemm_proj<<<dim3(KLEN / 64, DM / 64), 256, 0, stream>>>(
      p, Wp, r_, KLEN, KLEN, 0);
  k_attn<<<dim3(QLEN / BQ, NHEAD, B_SZ), 256, 0, stream>>>(
      q_, k_, v_, r_, bk, br, ao);
  k_gemm_out<<<dim3(B_SZ * QLEN / 64, DM / 64), 256, 0, stream>>>(ao, Wo, out);
}

// Round 2
// 400.718 us; speedup vs baseline: 10.3044x; 10.3044x over previous
//
#include <hip/hip_runtime.h>
#include <hip/hip_bf16.h>
#include <stddef.h>

#define DM    512
#define NHEAD 8
#define DHEAD 64
#define QLEN  1024
#define KLEN  2048
#define MLEN  1024
#define B_SZ  4

typedef __attribute__((ext_vector_type(8))) short short8;
typedef __attribute__((ext_vector_type(4))) float floatx4;
typedef __attribute__((ext_vector_type(4))) unsigned short ushort4v;

static __device__ __forceinline__ unsigned short f2bf(float f) {
  unsigned int u = __float_as_uint(f);
  unsigned int r = (u + 0x7FFFu + ((u >> 16) & 1u)) >> 16;
  return (unsigned short)r;
}
static __device__ __forceinline__ float bf2f(unsigned short h) {
  return __uint_as_float(((unsigned int)h) << 16);
}

// ---------------------------------------------------------------------------
// C_bf16[M][512] = A'[M][512] * W[512][512]  (f32 compute, bf16 store)
// A' row m -> A row (m / rpbOut)*rpbIn + (m % rpbOut) + rowOff
// ---------------------------------------------------------------------------
__global__ __launch_bounds__(256) void k_gemm_proj(
    const float* __restrict__ A, const float* __restrict__ W,
    unsigned short* __restrict__ C, int rpbOut, int rpbIn, int rowOff) {
  __shared__ alignas(16) float As[16][64];
  __shared__ alignas(16) float Bs[16][64];
  const int tid = threadIdx.x;
  const int bm = blockIdx.x, bn = blockIdx.y;
  const int tx = tid & 15, ty = tid >> 4;
  const int arow = tid >> 2;
  const int acol = (tid & 3) << 2;
  const int brow = tid >> 4;
  const int bcol = (tid & 15) << 2;
  const int m = bm * 64 + arow;
  const size_t gr = (size_t)(m / rpbOut) * rpbIn + (m % rpbOut) + rowOff;
  const float* Arow = A + gr * DM;
  float acc[4][4] = {};
  for (int k0 = 0; k0 < DM; k0 += 16) {
    float4 a4 = *(const float4*)(Arow + k0 + acol);
    As[acol + 0][arow] = a4.x;
    As[acol + 1][arow] = a4.y;
    As[acol + 2][arow] = a4.z;
    As[acol + 3][arow] = a4.w;
    *(float4*)&Bs[brow][bcol] =
        *(const float4*)(W + (size_t)(k0 + brow) * DM + bn * 64 + bcol);
    __syncthreads();
#pragma unroll
    for (int kk = 0; kk < 16; ++kk) {
      float4 a = *(const float4*)&As[kk][ty << 2];
      float4 b = *(const float4*)&Bs[kk][tx << 2];
      acc[0][0] = fmaf(a.x, b.x, acc[0][0]);
      acc[0][1] = fmaf(a.x, b.y, acc[0][1]);
      acc[0][2] = fmaf(a.x, b.z, acc[0][2]);
      acc[0][3] = fmaf(a.x, b.w, acc[0][3]);
      acc[1][0] = fmaf(a.y, b.x, acc[1][0]);
      acc[1][1] = fmaf(a.y, b.y, acc[1][1]);
      acc[1][2] = fmaf(a.y, b.z, acc[1][2]);
      acc[1][3] = fmaf(a.y, b.w, acc[1][3]);
      acc[2][0] = fmaf(a.z, b.x, acc[2][0]);
      acc[2][1] = fmaf(a.z, b.y, acc[2][1]);
      acc[2][2] = fmaf(a.z, b.z, acc[2][2]);
      acc[2][3] = fmaf(a.z, b.w, acc[2][3]);
      acc[3][0] = fmaf(a.w, b.x, acc[3][0]);
      acc[3][1] = fmaf(a.w, b.y, acc[3][1]);
      acc[3][2] = fmaf(a.w, b.z, acc[3][2]);
      acc[3][3] = fmaf(a.w, b.w, acc[3][3]);
    }
    __syncthreads();
  }
  unsigned short* Crow =
      C + (size_t)(bm * 64 + (ty << 2)) * DM + bn * 64 + (tx << 2);
#pragma unroll
  for (int i = 0; i < 4; ++i) {
    ushort4v o;
    o[0] = f2bf(acc[i][0]); o[1] = f2bf(acc[i][1]);
    o[2] = f2bf(acc[i][2]); o[3] = f2bf(acc[i][3]);
    *(ushort4v*)(Crow + (size_t)i * DM) = o;
  }
}

// ---------------------------------------------------------------------------
// out[4096][512] = A[4096][512] * Wo[512][512]^T   (f32)
// ---------------------------------------------------------------------------
__global__ __launch_bounds__(256) void k_gemm_out(
    const float* __restrict__ A, const float* __restrict__ W,
    float* __restrict__ C) {
  __shared__ alignas(16) float As[16][64];
  __shared__ alignas(16) float Bs[16][64];
  const int tid = threadIdx.x;
  const int bm = blockIdx.x, bn = blockIdx.y;
  const int tx = tid & 15, ty = tid >> 4;
  const int arow = tid >> 2;
  const int acol = (tid & 3) << 2;
  const int wrow = tid >> 2;
  const int wcol = (tid & 3) << 2;
  const float* Arow = A + (size_t)(bm * 64 + arow) * DM;
  float acc[4][4] = {};
  for (int k0 = 0; k0 < DM; k0 += 16) {
    float4 a4 = *(const float4*)(Arow + k0 + acol);
    As[acol + 0][arow] = a4.x;
    As[acol + 1][arow] = a4.y;
    As[acol + 2][arow] = a4.z;
    As[acol + 3][arow] = a4.w;
    float4 w4 = *(const float4*)(W + (size_t)(bn * 64 + wrow) * DM + k0 + wcol);
    Bs[wcol + 0][wrow] = w4.x;
    Bs[wcol + 1][wrow] = w4.y;
    Bs[wcol + 2][wrow] = w4.z;
    Bs[wcol + 3][wrow] = w4.w;
    __syncthreads();
#pragma unroll
    for (int kk = 0; kk < 16; ++kk) {
      float4 a = *(const float4*)&As[kk][ty << 2];
      float4 b = *(const float4*)&Bs[kk][tx << 2];
      acc[0][0] = fmaf(a.x, b.x, acc[0][0]);
      acc[0][1] = fmaf(a.x, b.y, acc[0][1]);
      acc[0][2] = fmaf(a.x, b.z, acc[0][2]);
      acc[0][3] = fmaf(a.x, b.w, acc[0][3]);
      acc[1][0] = fmaf(a.y, b.x, acc[1][0]);
      acc[1][1] = fmaf(a.y, b.y, acc[1][1]);
      acc[1][2] = fmaf(a.y, b.z, acc[1][2]);
      acc[1][3] = fmaf(a.y, b.w, acc[1][3]);
      acc[2][0] = fmaf(a.z, b.x, acc[2][0]);
      acc[2][1] = fmaf(a.z, b.y, acc[2][1]);
      acc[2][2] = fmaf(a.z, b.z, acc[2][2]);
      acc[2][3] = fmaf(a.z, b.w, acc[2][3]);
      acc[3][0] = fmaf(a.w, b.x, acc[3][0]);
      acc[3][1] = fmaf(a.w, b.y, acc[3][1]);
      acc[3][2] = fmaf(a.w, b.z, acc[3][2]);
      acc[3][3] = fmaf(a.w, b.w, acc[3][3]);
    }
    __syncthreads();
  }
  float* Crow = C + (size_t)(bm * 64 + (ty << 2)) * DM + bn * 64 + (tx << 2);
#pragma unroll
  for (int i = 0; i < 4; ++i) {
    float4 o;
    o.x = acc[i][0]; o.y = acc[i][1]; o.z = acc[i][2]; o.w = acc[i][3];
    *(float4*)(Crow + (size_t)i * DM) = o;
  }
}

// ---------------------------------------------------------------------------
// Flash-style MFMA attention. Block = (64 q rows, head n, batch b); 4 waves,
// wave w owns q rows [i0+16w, i0+16w+16). Logits pre-scaled by 1/8 via Q.
// score(i,j) = qk_i.k_j + qr_i.r[j-i+1023], valid j <= i+1024.
// ---------------------------------------------------------------------------
__global__ __launch_bounds__(256, 2) void k_attn_mfma(
    const unsigned short* __restrict__ q, const unsigned short* __restrict__ k,
    const unsigned short* __restrict__ v, const unsigned short* __restrict__ r,
    const float* __restrict__ bk, const float* __restrict__ br,
    float* __restrict__ ao) {
  __shared__ unsigned short VT[64][72];      // V^T tile, padded
  __shared__ unsigned short P[4][16][72];    // per-wave P (bf16), padded
  __shared__ float BD2[4][16][80];           // per-wave BD gather window

  const int tid = threadIdx.x;
  const int w = tid >> 6;
  const int lane = tid & 63;
  const int c = lane & 15;       // tile col (key / d)
  const int g = lane >> 4;       // k-group
  const int bx = blockIdx.x;
  const int ibx = bx >> 1;
  const int i0 = ((bx & 1) ? (15 - ibx) : ibx) * 64;   // work-balance pairing
  const int n = blockIdx.y;
  const int b = blockIdx.z;
  const int qb = i0 + w * 16;

  // Q fragments (row = c, k = g*8+j within each 32-half), biases added, *1/8
  short8 aqk[2], aqr[2];
  {
    const unsigned short* qrow =
        q + ((size_t)(b * QLEN) + qb + c) * DM + n * DHEAD;
#pragma unroll
    for (int kb = 0; kb < 2; ++kb) {
      short8 qv = *(const short8*)(qrow + kb * 32 + g * 8);
#pragma unroll
      for (int j = 0; j < 8; ++j) {
        int d = kb * 32 + g * 8 + j;
        float f = bf2f((unsigned short)qv[j]);
        aqk[kb][j] = (short)f2bf((f + bk[n * DHEAD + d]) * 0.125f);
        aqr[kb][j] = (short)f2bf((f + br[n * DHEAD + d]) * 0.125f);
      }
    }
  }

  floatx4 o[4];
#pragma unroll
  for (int t = 0; t < 4; ++t) o[t] = (floatx4){0.f, 0.f, 0.f, 0.f};
  float m[4], lsum[4];
#pragma unroll
  for (int rg = 0; rg < 4; ++rg) { m[rg] = -1e30f; lsum[rg] = 0.f; }

  const int nkb = i0 / 64 + 17;

  for (int t = 0; t < nkb; ++t) {
    const int j0 = t * 64;
    __syncthreads();
    // stage V^T (64 keys x 64 d -> VT[d][key])
    {
      const int key0 = tid >> 3;
      const int d0 = (tid & 7) * 8;
#pragma unroll
      for (int rep = 0; rep < 2; ++rep) {
        int kk = key0 + rep * 32;
        short8 vv = *(const short8*)(
            v + ((size_t)(b * KLEN) + j0 + kk) * DM + n * DHEAD + d0);
#pragma unroll
        for (int j = 0; j < 8; ++j)
          VT[d0 + j][kk] = (unsigned short)vv[j];
      }
    }
    __syncthreads();

    // BD tiles: BD2[q][jr - jrbase], jrbase = j0 - qb + 1008 (tile-aligned)
    const int jrbase = j0 - qb + 1008;
#pragma unroll
    for (int tau = 0; tau < 5; ++tau) {
      int jrow = jrbase + tau * 16 + c;
      jrow = min(jrow, KLEN - 1);
      const unsigned short* rr = r + (size_t)jrow * DM + n * DHEAD;
      short8 rb0 = *(const short8*)(rr + g * 8);
      short8 rb1 = *(const short8*)(rr + 32 + g * 8);
      floatx4 bd = (floatx4){0.f, 0.f, 0.f, 0.f};
      bd = __builtin_amdgcn_mfma_f32_16x16x32_bf16(aqr[0], rb0, bd, 0, 0, 0);
      bd = __builtin_amdgcn_mfma_f32_16x16x32_bf16(aqr[1], rb1, bd, 0, 0, 0);
#pragma unroll
      for (int rg = 0; rg < 4; ++rg)
        BD2[w][4 * g + rg][tau * 16 + c] = bd[rg];
    }

    // AC tiles + BD gather + mask
    floatx4 s[4];
    const bool lastblk = (t == nkb - 1);
#pragma unroll
    for (int tau = 0; tau < 4; ++tau) {
      const unsigned short* kr =
          k + ((size_t)(b * KLEN) + j0 + tau * 16 + c) * DM + n * DHEAD;
      short8 kb0 = *(const short8*)(kr + g * 8);
      short8 kb1 = *(const short8*)(kr + 32 + g * 8);
      floatx4 acc = (floatx4){0.f, 0.f, 0.f, 0.f};
      acc = __builtin_amdgcn_mfma_f32_16x16x32_bf16(aqk[0], kb0, acc, 0, 0, 0);
      acc = __builtin_amdgcn_mfma_f32_16x16x32_bf16(aqk[1], kb1, acc, 0, 0, 0);
#pragma unroll
      for (int rg = 0; rg < 4; ++rg) {
        int ql = 4 * g + rg;
        int idx = 15 + tau * 16 + c - ql;   // (j0+tau*16+c) - ql - qb + 1023 - jrbase
        float sv = acc[rg] + BD2[w][ql][idx];
        if (lastblk && (tau * 16 + c > w * 16 + ql)) sv = -1e30f;
        s[tau][rg] = sv;
      }
    }

    // online softmax (logits already scaled)
    float fac[4];
#pragma unroll
    for (int rg = 0; rg < 4; ++rg) {
      float mx = fmaxf(fmaxf(s[0][rg], s[1][rg]), fmaxf(s[2][rg], s[3][rg]));
#pragma unroll
      for (int sh = 1; sh < 16; sh <<= 1) mx = fmaxf(mx, __shfl_xor(mx, sh, 64));
      float mn = fmaxf(m[rg], mx);
      fac[rg] = __expf(m[rg] - mn);
      m[rg] = mn;
    }
    float rsum[4] = {0.f, 0.f, 0.f, 0.f};
#pragma unroll
    for (int tau = 0; tau < 4; ++tau) {
#pragma unroll
      for (int rg = 0; rg < 4; ++rg) {
        float p = __expf(s[tau][rg] - m[rg]);
        rsum[rg] += p;
        P[w][4 * g + rg][tau * 16 + c] = f2bf(p);
      }
    }
#pragma unroll
    for (int rg = 0; rg < 4; ++rg) {
      float rs = rsum[rg];
#pragma unroll
      for (int sh = 1; sh < 16; sh <<= 1) rs += __shfl_xor(rs, sh, 64);
      lsum[rg] = lsum[rg] * fac[rg] + rs;
#pragma unroll
      for (int td = 0; td < 4; ++td) o[td][rg] *= fac[rg];
    }

    // PV
    short8 pa0 = *(const short8*)&P[w][c][g * 8];
    short8 pa1 = *(const short8*)&P[w][c][32 + g * 8];
#pragma unroll
    for (int td = 0; td < 4; ++td) {
      short8 vb0 = *(const short8*)&VT[td * 16 + c][g * 8];
      short8 vb1 = *(const short8*)&VT[td * 16 + c][32 + g * 8];
      o[td] = __builtin_amdgcn_mfma_f32_16x16x32_bf16(pa0, vb0, o[td], 0, 0, 0);
      o[td] = __builtin_amdgcn_mfma_f32_16x16x32_bf16(pa1, vb1, o[td], 0, 0, 0);
    }
  }

  // epilogue
#pragma unroll
  for (int td = 0; td < 4; ++td) {
#pragma unroll
    for (int rg = 0; rg < 4; ++rg) {
      float val = o[td][rg] / lsum[rg];
      ao[((size_t)(b * QLEN) + qb + 4 * g + rg) * DM + n * DHEAD + td * 16 + c] =
          val;
    }
  }
}

// ---------------------------------------------------------------------------
extern "C" void kernel_launch(void* const* d_in, const int* in_sizes, int n_in,
                              void* d_out, int out_size, void* d_ws, size_t ws_size,
                              hipStream_t stream) {
  const float* x  = (const float*)d_in[0];
  const float* p  = (const float*)d_in[1];
  const float* Wq = (const float*)d_in[2];
  const float* Wk = (const float*)d_in[3];
  const float* Wv = (const float*)d_in[4];
  const float* Wo = (const float*)d_in[5];
  const float* Wp = (const float*)d_in[6];
  const float* bk = (const float*)d_in[7];
  const float* br = (const float*)d_in[8];
  float* out = (float*)d_out;

  unsigned short* q_ = (unsigned short*)d_ws;               // [4096][512] bf16
  unsigned short* k_ = q_ + (size_t)B_SZ * QLEN * DM;       // [8192][512] bf16
  unsigned short* v_ = k_ + (size_t)B_SZ * KLEN * DM;       // [8192][512] bf16
  unsigned short* r_ = v_ + (size_t)B_SZ * KLEN * DM;       // [2048][512] bf16
  float* ao = (float*)(r_ + (size_t)KLEN * DM);             // [4096][512] f32

  k_gemm_proj<<<dim3(B_SZ * QLEN / 64, DM / 64), 256, 0, stream>>>(
      x, Wq, q_, QLEN, KLEN, MLEN);
  k_gemm_proj<<<dim3(B_SZ * KLEN / 64, DM / 64), 256, 0, stream>>>(
      x, Wk, k_, KLEN, KLEN, 0);
  k_gemm_proj<<<dim3(B_SZ * KLEN / 64, DM / 64), 256, 0, stream>>>(
      x, Wv, v_, KLEN, KLEN, 0);
  k_gemm_proj<<<dim3(KLEN / 64, DM / 64), 256, 0, stream>>>(
      p, Wp, r_, KLEN, KLEN, 0);
  k_attn_mfma<<<dim3(QLEN / 64, NHEAD, B_SZ), 256, 0, stream>>>(
      q_, k_, v_, r_, bk, br, ao);
  k_gemm_out<<<dim3(B_SZ * QLEN / 64, DM / 64), 256, 0, stream>>>(ao, Wo, out);
}

// Round 3
// 198.836 us; speedup vs baseline: 20.7668x; 2.0153x over previous
//
#include <hip/hip_runtime.h>
#include <hip/hip_bf16.h>
#include <stddef.h>
#include <stdint.h>

#define DM    512
#define NHEAD 8
#define DHEAD 64
#define QLEN  1024
#define KLEN  2048
#define MLEN  1024
#define B_SZ  4

typedef __attribute__((ext_vector_type(8))) short short8;
typedef __attribute__((ext_vector_type(8))) unsigned short ushort8;
typedef __attribute__((ext_vector_type(4))) float floatx4;

static __device__ __forceinline__ unsigned short f2bf(float f) {
  unsigned int u = __float_as_uint(f);
  unsigned int r = (u + 0x7FFFu + ((u >> 16) & 1u)) >> 16;
  return (unsigned short)r;
}
static __device__ __forceinline__ float bf2f(unsigned short h) {
  return __uint_as_float(((unsigned int)h) << 16);
}

#define GLOAD_LDS16(gsrc, ldst)                                               \
  __builtin_amdgcn_global_load_lds(                                           \
      (const __attribute__((address_space(1))) unsigned int*)(gsrc),          \
      (__attribute__((address_space(3))) unsigned int*)(ldst), 16, 0, 0)

// ---------------------------------------------------------------------------
// f32 -> bf16 elementwise (8 per thread)
// ---------------------------------------------------------------------------
__global__ __launch_bounds__(256) void k_f32bf16(
    const float* __restrict__ in, unsigned short* __restrict__ out, int n8) {
  int i = blockIdx.x * 256 + threadIdx.x;
  if (i < n8) {
    float4 a = *(const float4*)(in + (size_t)i * 8);
    float4 b = *(const float4*)(in + (size_t)i * 8 + 4);
    ushort8 o;
    o[0] = f2bf(a.x); o[1] = f2bf(a.y); o[2] = f2bf(a.z); o[3] = f2bf(a.w);
    o[4] = f2bf(b.x); o[5] = f2bf(b.y); o[6] = f2bf(b.z); o[7] = f2bf(b.w);
    *(ushort8*)(out + (size_t)i * 8) = o;
  }
}

// ---------------------------------------------------------------------------
// Transpose-convert the 4 projection weights: W[512 k][512 n] f32 ->
// Wt[512 n][512 k] bf16 (4 matrices stacked, stride 262144).
// ---------------------------------------------------------------------------
__global__ __launch_bounds__(256) void k_wtrans(
    const float* __restrict__ W0, const float* __restrict__ W1,
    const float* __restrict__ W2, const float* __restrict__ W3,
    unsigned short* __restrict__ wt) {
  __shared__ float tile[64][65];
  const int z = blockIdx.z;
  const float* W = (z == 0) ? W0 : (z == 1) ? W1 : (z == 2) ? W2 : W3;
  unsigned short* out = wt + (size_t)z * 262144;
  const int tid = threadIdx.x;
  const int row = tid >> 2, c0 = (tid & 3) * 16;
  const int kb = blockIdx.y * 64, nb = blockIdx.x * 64;
#pragma unroll
  for (int j = 0; j < 4; ++j) {
    float4 ld = *(const float4*)(W + (size_t)(kb + row) * DM + nb + c0 + j * 4);
    tile[row][c0 + j * 4 + 0] = ld.x;
    tile[row][c0 + j * 4 + 1] = ld.y;
    tile[row][c0 + j * 4 + 2] = ld.z;
    tile[row][c0 + j * 4 + 3] = ld.w;
  }
  __syncthreads();
  unsigned short ob[16];
#pragma unroll
  for (int j = 0; j < 16; ++j) ob[j] = f2bf(tile[c0 + j][row]);
  unsigned short* orow = out + (size_t)(nb + row) * DM + kb + c0;
  *(ushort8*)(orow) = *(ushort8*)&ob[0];
  *(ushort8*)(orow + 8) = *(ushort8*)&ob[8];
}

// ---------------------------------------------------------------------------
// Fused bf16 MFMA projection GEMM: C[M][512] = A[M][512] * Wt[512][512]^T
// 128x128 tile, BK=64, 4 waves (2x2 of 64x64), global_load_lds staging with
// (row&7) XOR-of-16B-slot swizzle (pre-swizzled global source, linear LDS).
// Problems packed on blockIdx.x: q(32) | k(64) | v(64) | r(16).
// ---------------------------------------------------------------------------
__global__ __launch_bounds__(256) void k_proj_mfma(
    const unsigned short* __restrict__ xb, const unsigned short* __restrict__ pb,
    const unsigned short* __restrict__ wt,
    unsigned short* __restrict__ q_, unsigned short* __restrict__ k_,
    unsigned short* __restrict__ v_, unsigned short* __restrict__ r_) {
  __shared__ unsigned short Abuf[128 * 64];
  __shared__ unsigned short Bbuf[128 * 64];
  const int tid = threadIdx.x, w = tid >> 6, lane = tid & 63;
  const int c = lane & 15, g = lane >> 4;
  const int wr = w >> 1, wc = w & 1;
  const int mb = blockIdx.x, nb = blockIdx.y;
  int prob, mloc;
  const unsigned short* A;
  unsigned short* C;
  if (mb < 32)        { prob = 0; mloc = mb;       A = xb; C = q_; }
  else if (mb < 96)   { prob = 1; mloc = mb - 32;  A = xb; C = k_; }
  else if (mb < 160)  { prob = 2; mloc = mb - 96;  A = xb; C = v_; }
  else                { prob = 3; mloc = mb - 160; A = pb; C = r_; }
  const unsigned short* W = wt + (size_t)prob * 262144;
  const int m0 = mloc * 128;
  const int lrow = lane >> 3, lslot = lane & 7;

  floatx4 acc[4][4];
#pragma unroll
  for (int m = 0; m < 4; ++m)
#pragma unroll
    for (int nn = 0; nn < 4; ++nn) acc[m][nn] = (floatx4){0.f, 0.f, 0.f, 0.f};

  for (int k0 = 0; k0 < DM; k0 += 64) {
    __syncthreads();
#pragma unroll
    for (int iq = 0; iq < 4; ++iq) {
      const int r0 = w * 32 + iq * 8;
      const int arow = r0 + lrow;
      const int mrow = m0 + arow;
      const int grow =
          (prob == 0) ? ((mrow >> 10) * KLEN + (mrow & 1023) + MLEN) : mrow;
      const int sgA = lslot ^ (arow & 7);
      GLOAD_LDS16(A + (size_t)grow * DM + k0 + sgA * 8, Abuf + r0 * 64);
      const int nrow = nb * 128 + arow;
      const int sgB = lslot ^ (arow & 7);
      GLOAD_LDS16(W + (size_t)nrow * DM + k0 + sgB * 8, Bbuf + r0 * 64);
    }
    __syncthreads();
#pragma unroll
    for (int kk = 0; kk < 2; ++kk) {
      short8 af[4], bf[4];
#pragma unroll
      for (int m = 0; m < 4; ++m) {
        const int arow = wr * 64 + m * 16 + c;
        const int slot = (kk * 4 + g) ^ (arow & 7);
        af[m] = *(const short8*)(Abuf + arow * 64 + slot * 8);
      }
#pragma unroll
      for (int nn = 0; nn < 4; ++nn) {
        const int brow = wc * 64 + nn * 16 + c;
        const int slot = (kk * 4 + g) ^ (brow & 7);
        bf[nn] = *(const short8*)(Bbuf + brow * 64 + slot * 8);
      }
#pragma unroll
      for (int m = 0; m < 4; ++m)
#pragma unroll
        for (int nn = 0; nn < 4; ++nn)
          acc[m][nn] = __builtin_amdgcn_mfma_f32_16x16x32_bf16(
              af[m], bf[nn], acc[m][nn], 0, 0, 0);
    }
  }
#pragma unroll
  for (int m = 0; m < 4; ++m)
#pragma unroll
    for (int nn = 0; nn < 4; ++nn)
#pragma unroll
      for (int rg = 0; rg < 4; ++rg) {
        const int row = m0 + wr * 64 + m * 16 + 4 * g + rg;
        const int col = nb * 128 + wc * 64 + nn * 16 + c;
        C[(size_t)row * DM + col] = f2bf(acc[m][nn][rg]);
      }
}

// ---------------------------------------------------------------------------
// out[4096][512] = A[4096][512] * Wo[512][512]^T   (f32)
// ---------------------------------------------------------------------------
__global__ __launch_bounds__(256) void k_gemm_out(
    const float* __restrict__ A, const float* __restrict__ W,
    float* __restrict__ C) {
  __shared__ alignas(16) float As[16][64];
  __shared__ alignas(16) float Bs[16][64];
  const int tid = threadIdx.x;
  const int bm = blockIdx.x, bn = blockIdx.y;
  const int tx = tid & 15, ty = tid >> 4;
  const int arow = tid >> 2;
  const int acol = (tid & 3) << 2;
  const int wrow = tid >> 2;
  const int wcol = (tid & 3) << 2;
  const float* Arow = A + (size_t)(bm * 64 + arow) * DM;
  float acc[4][4] = {};
  for (int k0 = 0; k0 < DM; k0 += 16) {
    float4 a4 = *(const float4*)(Arow + k0 + acol);
    As[acol + 0][arow] = a4.x;
    As[acol + 1][arow] = a4.y;
    As[acol + 2][arow] = a4.z;
    As[acol + 3][arow] = a4.w;
    float4 w4 = *(const float4*)(W + (size_t)(bn * 64 + wrow) * DM + k0 + wcol);
    Bs[wcol + 0][wrow] = w4.x;
    Bs[wcol + 1][wrow] = w4.y;
    Bs[wcol + 2][wrow] = w4.z;
    Bs[wcol + 3][wrow] = w4.w;
    __syncthreads();
#pragma unroll
    for (int kk = 0; kk < 16; ++kk) {
      float4 a = *(const float4*)&As[kk][ty << 2];
      float4 b = *(const float4*)&Bs[kk][tx << 2];
      acc[0][0] = fmaf(a.x, b.x, acc[0][0]);
      acc[0][1] = fmaf(a.x, b.y, acc[0][1]);
      acc[0][2] = fmaf(a.x, b.z, acc[0][2]);
      acc[0][3] = fmaf(a.x, b.w, acc[0][3]);
      acc[1][0] = fmaf(a.y, b.x, acc[1][0]);
      acc[1][1] = fmaf(a.y, b.y, acc[1][1]);
      acc[1][2] = fmaf(a.y, b.z, acc[1][2]);
      acc[1][3] = fmaf(a.y, b.w, acc[1][3]);
      acc[2][0] = fmaf(a.z, b.x, acc[2][0]);
      acc[2][1] = fmaf(a.z, b.y, acc[2][1]);
      acc[2][2] = fmaf(a.z, b.z, acc[2][2]);
      acc[2][3] = fmaf(a.z, b.w, acc[2][3]);
      acc[3][0] = fmaf(a.w, b.x, acc[3][0]);
      acc[3][1] = fmaf(a.w, b.y, acc[3][1]);
      acc[3][2] = fmaf(a.w, b.z, acc[3][2]);
      acc[3][3] = fmaf(a.w, b.w, acc[3][3]);
    }
    __syncthreads();
  }
  float* Crow = C + (size_t)(bm * 64 + (ty << 2)) * DM + bn * 64 + (tx << 2);
#pragma unroll
  for (int i = 0; i < 4; ++i) {
    float4 o;
    o.x = acc[i][0]; o.y = acc[i][1]; o.z = acc[i][2]; o.w = acc[i][3];
    *(float4*)(Crow + (size_t)i * DM) = o;
  }
}

// ---------------------------------------------------------------------------
// Flash-style MFMA attention (64 q rows / block, 4 waves x 16 rows).
// score(i,j) = qk_i.k_j + qr_i.r[j-i+1023], valid j <= i+1024.
// ---------------------------------------------------------------------------
__global__ __launch_bounds__(256) void k_attn_mfma(
    const unsigned short* __restrict__ q, const unsigned short* __restrict__ k,
    const unsigned short* __restrict__ v, const unsigned short* __restrict__ r,
    const float* __restrict__ bk, const float* __restrict__ br,
    float* __restrict__ ao) {
  __shared__ unsigned short VT[64][74];      // V^T tile (pad 74: ~2-way max)
  __shared__ unsigned short P[4][16][76];    // per-wave P bf16 (pad 76)
  __shared__ float BD2[4][16][83];           // per-wave BD window (pad 83)

  const int tid = threadIdx.x;
  const int w = tid >> 6;
  const int lane = tid & 63;
  const int c = lane & 15;
  const int g = lane >> 4;
  const int n = blockIdx.y;
  const int b = blockIdx.z;
  const int grp = (n + NHEAD * b) >> 4;              // balance across co-resident blocks
  const int i0 = (grp ? (15 - blockIdx.x) : blockIdx.x) * 64;
  const int qb = i0 + w * 16;

  short8 aqk[2], aqr[2];
  {
    const unsigned short* qrow =
        q + ((size_t)(b * QLEN) + qb + c) * DM + n * DHEAD;
#pragma unroll
    for (int kb2 = 0; kb2 < 2; ++kb2) {
      short8 qv = *(const short8*)(qrow + kb2 * 32 + g * 8);
#pragma unroll
      for (int j = 0; j < 8; ++j) {
        int d = kb2 * 32 + g * 8 + j;
        float f = bf2f((unsigned short)qv[j]);
        aqk[kb2][j] = (short)f2bf((f + bk[n * DHEAD + d]) * 0.125f);
        aqr[kb2][j] = (short)f2bf((f + br[n * DHEAD + d]) * 0.125f);
      }
    }
  }

  floatx4 o[4];
#pragma unroll
  for (int t = 0; t < 4; ++t) o[t] = (floatx4){0.f, 0.f, 0.f, 0.f};
  float m[4], lsum[4];
#pragma unroll
  for (int rg = 0; rg < 4; ++rg) { m[rg] = -1e30f; lsum[rg] = 0.f; }

  const int nkb = i0 / 64 + 17;
  const int key0 = tid >> 3, d0 = (tid & 7) * 8;

  short8 vcur[2];
  vcur[0] = *(const short8*)(v + ((size_t)(b * KLEN) + key0) * DM + n * DHEAD + d0);
  vcur[1] = *(const short8*)(v + ((size_t)(b * KLEN) + key0 + 32) * DM + n * DHEAD + d0);

  for (int t = 0; t < nkb; ++t) {
    const int j0 = t * 64;
    __syncthreads();
    // write V^T from prefetched regs
#pragma unroll
    for (int rep = 0; rep < 2; ++rep)
#pragma unroll
      for (int j = 0; j < 8; ++j)
        VT[d0 + j][key0 + rep * 32] = (unsigned short)vcur[rep][j];
    // prefetch next tile's V
    short8 vnext[2];
    if (t + 1 < nkb) {
      vnext[0] = *(const short8*)(
          v + ((size_t)(b * KLEN) + j0 + 64 + key0) * DM + n * DHEAD + d0);
      vnext[1] = *(const short8*)(
          v + ((size_t)(b * KLEN) + j0 + 96 + key0) * DM + n * DHEAD + d0);
    }
    // hoist all K fragments
    short8 kf[4][2];
#pragma unroll
    for (int tau = 0; tau < 4; ++tau) {
      const unsigned short* kr =
          k + ((size_t)(b * KLEN) + j0 + tau * 16 + c) * DM + n * DHEAD;
      kf[tau][0] = *(const short8*)(kr + g * 8);
      kf[tau][1] = *(const short8*)(kr + 32 + g * 8);
    }
    // hoist all R fragments
    const int jrbase = j0 - qb + 1008;
    short8 rf[5][2];
#pragma unroll
    for (int tau = 0; tau < 5; ++tau) {
      int jrow = min(jrbase + tau * 16 + c, KLEN - 1);
      const unsigned short* rr = r + (size_t)jrow * DM + n * DHEAD;
      rf[tau][0] = *(const short8*)(rr + g * 8);
      rf[tau][1] = *(const short8*)(rr + 32 + g * 8);
    }
    __syncthreads();   // VT ready

    // BD tiles
#pragma unroll
    for (int tau = 0; tau < 5; ++tau) {
      floatx4 bd = (floatx4){0.f, 0.f, 0.f, 0.f};
      bd = __builtin_amdgcn_mfma_f32_16x16x32_bf16(aqr[0], rf[tau][0], bd, 0, 0, 0);
      bd = __builtin_amdgcn_mfma_f32_16x16x32_bf16(aqr[1], rf[tau][1], bd, 0, 0, 0);
#pragma unroll
      for (int rg = 0; rg < 4; ++rg)
        BD2[w][4 * g + rg][tau * 16 + c] = bd[rg];
    }

    // AC tiles + BD gather + mask
    floatx4 s[4];
    const bool lastblk = (t == nkb - 1);
#pragma unroll
    for (int tau = 0; tau < 4; ++tau) {
      floatx4 acc = (floatx4){0.f, 0.f, 0.f, 0.f};
      acc = __builtin_amdgcn_mfma_f32_16x16x32_bf16(aqk[0], kf[tau][0], acc, 0, 0, 0);
      acc = __builtin_amdgcn_mfma_f32_16x16x32_bf16(aqk[1], kf[tau][1], acc, 0, 0, 0);
#pragma unroll
      for (int rg = 0; rg < 4; ++rg) {
        int ql = 4 * g + rg;
        int idx = 15 + tau * 16 + c - ql;
        float sv = acc[rg] + BD2[w][ql][idx];
        if (lastblk && (tau * 16 + c > w * 16 + ql)) sv = -1e30f;
        s[tau][rg] = sv;
      }
    }

    // online softmax
    float fac[4];
#pragma unroll
    for (int rg = 0; rg < 4; ++rg) {
      float mx = fmaxf(fmaxf(s[0][rg], s[1][rg]), fmaxf(s[2][rg], s[3][rg]));
#pragma unroll
      for (int sh = 1; sh < 16; sh <<= 1) mx = fmaxf(mx, __shfl_xor(mx, sh, 64));
      float mn = fmaxf(m[rg], mx);
      fac[rg] = __expf(m[rg] - mn);
      m[rg] = mn;
    }
    float rsum[4] = {0.f, 0.f, 0.f, 0.f};
#pragma unroll
    for (int tau = 0; tau < 4; ++tau) {
#pragma unroll
      for (int rg = 0; rg < 4; ++rg) {
        float p = __expf(s[tau][rg] - m[rg]);
        rsum[rg] += p;
        P[w][4 * g + rg][tau * 16 + c] = f2bf(p);
      }
    }
#pragma unroll
    for (int rg = 0; rg < 4; ++rg) {
      float rs = rsum[rg];
#pragma unroll
      for (int sh = 1; sh < 16; sh <<= 1) rs += __shfl_xor(rs, sh, 64);
      lsum[rg] = lsum[rg] * fac[rg] + rs;
#pragma unroll
      for (int td = 0; td < 4; ++td) o[td][rg] *= fac[rg];
    }

    // PV
    short8 pa0 = *(const short8*)&P[w][c][g * 8];
    short8 pa1 = *(const short8*)&P[w][c][32 + g * 8];
#pragma unroll
    for (int td = 0; td < 4; ++td) {
      short8 vb0 = *(const short8*)&VT[td * 16 + c][g * 8];
      short8 vb1 = *(const short8*)&VT[td * 16 + c][32 + g * 8];
      o[td] = __builtin_amdgcn_mfma_f32_16x16x32_bf16(pa0, vb0, o[td], 0, 0, 0);
      o[td] = __builtin_amdgcn_mfma_f32_16x16x32_bf16(pa1, vb1, o[td], 0, 0, 0);
    }
    if (t + 1 < nkb) { vcur[0] = vnext[0]; vcur[1] = vnext[1]; }
  }

#pragma unroll
  for (int td = 0; td < 4; ++td)
#pragma unroll
    for (int rg = 0; rg < 4; ++rg) {
      float val = o[td][rg] / lsum[rg];
      ao[((size_t)(b * QLEN) + qb + 4 * g + rg) * DM + n * DHEAD + td * 16 + c] =
          val;
    }
}

// ---------------------------------------------------------------------------
extern "C" void kernel_launch(void* const* d_in, const int* in_sizes, int n_in,
                              void* d_out, int out_size, void* d_ws, size_t ws_size,
                              hipStream_t stream) {
  const float* x  = (const float*)d_in[0];
  const float* p  = (const float*)d_in[1];
  const float* Wq = (const float*)d_in[2];
  const float* Wk = (const float*)d_in[3];
  const float* Wv = (const float*)d_in[4];
  const float* Wo = (const float*)d_in[5];
  const float* Wp = (const float*)d_in[6];
  const float* bk = (const float*)d_in[7];
  const float* br = (const float*)d_in[8];
  float* out = (float*)d_out;

  unsigned short* q_ = (unsigned short*)d_ws;         // 4096*512
  unsigned short* k_ = q_ + (size_t)4096 * 512;       // 8192*512
  unsigned short* v_ = k_ + (size_t)8192 * 512;       // 8192*512
  unsigned short* r_ = v_ + (size_t)8192 * 512;       // 2048*512
  unsigned short* xb = r_ + (size_t)2048 * 512;       // 8192*512
  unsigned short* pb = xb + (size_t)8192 * 512;       // 2048*512
  unsigned short* wt = pb + (size_t)2048 * 512;       // 4*512*512
  float* ao = (float*)(wt + (size_t)4 * 512 * 512);   // 4096*512 f32

  k_f32bf16<<<2048, 256, 0, stream>>>(x, xb, (B_SZ * KLEN * DM) / 8);
  k_f32bf16<<<512, 256, 0, stream>>>(p, pb, (KLEN * DM) / 8);
  k_wtrans<<<dim3(8, 8, 4), 256, 0, stream>>>(Wq, Wk, Wv, Wp, wt);
  k_proj_mfma<<<dim3(176, 4), 256, 0, stream>>>(xb, pb, wt, q_, k_, v_, r_);
  k_attn_mfma<<<dim3(QLEN / 64, NHEAD, B_SZ), 256, 0, stream>>>(
      q_, k_, v_, r_, bk, br, ao);
  k_gemm_out<<<dim3(B_SZ * QLEN / 64, DM / 64), 256, 0, stream>>>(ao, Wo, out);
}

// Round 4
// 183.037 us; speedup vs baseline: 22.5593x; 1.0863x over previous
//
#include <hip/hip_runtime.h>
#include <hip/hip_bf16.h>
#include <stddef.h>
#include <stdint.h>

#define DM    512
#define NHEAD 8
#define DHEAD 64
#define QLEN  1024
#define KLEN  2048
#define MLEN  1024
#define B_SZ  4

typedef __attribute__((ext_vector_type(8))) short short8;
typedef __attribute__((ext_vector_type(8))) unsigned short ushort8;
typedef __attribute__((ext_vector_type(4))) float floatx4;

static __device__ __forceinline__ unsigned short f2bf(float f) {
  unsigned int u = __float_as_uint(f);
  unsigned int r = (u + 0x7FFFu + ((u >> 16) & 1u)) >> 16;
  return (unsigned short)r;
}
static __device__ __forceinline__ float bf2f(unsigned short h) {
  return __uint_as_float(((unsigned int)h) << 16);
}

#define GLOAD_LDS16(gsrc, ldst)                                               \
  __builtin_amdgcn_global_load_lds(                                           \
      (const __attribute__((address_space(1))) unsigned int*)(gsrc),          \
      (__attribute__((address_space(3))) unsigned int*)(ldst), 16, 0, 0)

// ---------------------------------------------------------------------------
// f32 -> bf16 elementwise (8 per thread)
// ---------------------------------------------------------------------------
__global__ __launch_bounds__(256) void k_f32bf16(
    const float* __restrict__ in, unsigned short* __restrict__ out, int n8) {
  int i = blockIdx.x * 256 + threadIdx.x;
  if (i < n8) {
    float4 a = *(const float4*)(in + (size_t)i * 8);
    float4 b = *(const float4*)(in + (size_t)i * 8 + 4);
    ushort8 o;
    o[0] = f2bf(a.x); o[1] = f2bf(a.y); o[2] = f2bf(a.z); o[3] = f2bf(a.w);
    o[4] = f2bf(b.x); o[5] = f2bf(b.y); o[6] = f2bf(b.z); o[7] = f2bf(b.w);
    *(ushort8*)(out + (size_t)i * 8) = o;
  }
}

// ---------------------------------------------------------------------------
// f32 -> (hi, lo) bf16 split
// ---------------------------------------------------------------------------
__global__ __launch_bounds__(256) void k_wosplit(
    const float* __restrict__ in, unsigned short* __restrict__ oh,
    unsigned short* __restrict__ ol, int n8) {
  int i = blockIdx.x * 256 + threadIdx.x;
  if (i < n8) {
    ushort8 vh, vl;
#pragma unroll
    for (int j = 0; j < 8; ++j) {
      float f = in[(size_t)i * 8 + j];
      unsigned short h = f2bf(f);
      vh[j] = h;
      vl[j] = f2bf(f - bf2f(h));
    }
    *(ushort8*)(oh + (size_t)i * 8) = vh;
    *(ushort8*)(ol + (size_t)i * 8) = vl;
  }
}

// ---------------------------------------------------------------------------
// Transpose-convert the 4 projection weights: W[512 k][512 n] f32 ->
// Wt[512 n][512 k] bf16 (4 matrices stacked, stride 262144).
// ---------------------------------------------------------------------------
__global__ __launch_bounds__(256) void k_wtrans(
    const float* __restrict__ W0, const float* __restrict__ W1,
    const float* __restrict__ W2, const float* __restrict__ W3,
    unsigned short* __restrict__ wt) {
  __shared__ float tile[64][65];
  const int z = blockIdx.z;
  const float* W = (z == 0) ? W0 : (z == 1) ? W1 : (z == 2) ? W2 : W3;
  unsigned short* out = wt + (size_t)z * 262144;
  const int tid = threadIdx.x;
  const int row = tid >> 2, c0 = (tid & 3) * 16;
  const int kb = blockIdx.y * 64, nb = blockIdx.x * 64;
#pragma unroll
  for (int j = 0; j < 4; ++j) {
    float4 ld = *(const float4*)(W + (size_t)(kb + row) * DM + nb + c0 + j * 4);
    tile[row][c0 + j * 4 + 0] = ld.x;
    tile[row][c0 + j * 4 + 1] = ld.y;
    tile[row][c0 + j * 4 + 2] = ld.z;
    tile[row][c0 + j * 4 + 3] = ld.w;
  }
  __syncthreads();
  unsigned short ob[16];
#pragma unroll
  for (int j = 0; j < 16; ++j) ob[j] = f2bf(tile[c0 + j][row]);
  unsigned short* orow = out + (size_t)(nb + row) * DM + kb + c0;
  *(ushort8*)(orow) = *(ushort8*)&ob[0];
  *(ushort8*)(orow + 8) = *(ushort8*)&ob[8];
}

// ---------------------------------------------------------------------------
// Fused bf16 MFMA projection GEMM: C[M][512] = A[M][512] * Wt[512][512]^T
// ---------------------------------------------------------------------------
__global__ __launch_bounds__(256) void k_proj_mfma(
    const unsigned short* __restrict__ xb, const unsigned short* __restrict__ pb,
    const unsigned short* __restrict__ wt,
    unsigned short* __restrict__ q_, unsigned short* __restrict__ k_,
    unsigned short* __restrict__ v_, unsigned short* __restrict__ r_) {
  __shared__ unsigned short Abuf[128 * 64];
  __shared__ unsigned short Bbuf[128 * 64];
  const int tid = threadIdx.x, w = tid >> 6, lane = tid & 63;
  const int c = lane & 15, g = lane >> 4;
  const int wr = w >> 1, wc = w & 1;
  const int mb = blockIdx.x, nb = blockIdx.y;
  int prob, mloc;
  const unsigned short* A;
  unsigned short* C;
  if (mb < 32)        { prob = 0; mloc = mb;       A = xb; C = q_; }
  else if (mb < 96)   { prob = 1; mloc = mb - 32;  A = xb; C = k_; }
  else if (mb < 160)  { prob = 2; mloc = mb - 96;  A = xb; C = v_; }
  else                { prob = 3; mloc = mb - 160; A = pb; C = r_; }
  const unsigned short* W = wt + (size_t)prob * 262144;
  const int m0 = mloc * 128;
  const int lrow = lane >> 3, lslot = lane & 7;

  floatx4 acc[4][4];
#pragma unroll
  for (int m = 0; m < 4; ++m)
#pragma unroll
    for (int nn = 0; nn < 4; ++nn) acc[m][nn] = (floatx4){0.f, 0.f, 0.f, 0.f};

  for (int k0 = 0; k0 < DM; k0 += 64) {
    __syncthreads();
#pragma unroll
    for (int iq = 0; iq < 4; ++iq) {
      const int r0 = w * 32 + iq * 8;
      const int arow = r0 + lrow;
      const int mrow = m0 + arow;
      const int grow =
          (prob == 0) ? ((mrow >> 10) * KLEN + (mrow & 1023) + MLEN) : mrow;
      const int sgA = lslot ^ (arow & 7);
      GLOAD_LDS16(A + (size_t)grow * DM + k0 + sgA * 8, Abuf + r0 * 64);
      const int nrow = nb * 128 + arow;
      GLOAD_LDS16(W + (size_t)nrow * DM + k0 + sgA * 8, Bbuf + r0 * 64);
    }
    __syncthreads();
#pragma unroll
    for (int kk = 0; kk < 2; ++kk) {
      short8 af[4], bf[4];
#pragma unroll
      for (int m = 0; m < 4; ++m) {
        const int arow = wr * 64 + m * 16 + c;
        const int slot = (kk * 4 + g) ^ (arow & 7);
        af[m] = *(const short8*)(Abuf + arow * 64 + slot * 8);
      }
#pragma unroll
      for (int nn = 0; nn < 4; ++nn) {
        const int brow = wc * 64 + nn * 16 + c;
        const int slot = (kk * 4 + g) ^ (brow & 7);
        bf[nn] = *(const short8*)(Bbuf + brow * 64 + slot * 8);
      }
#pragma unroll
      for (int m = 0; m < 4; ++m)
#pragma unroll
        for (int nn = 0; nn < 4; ++nn)
          acc[m][nn] = __builtin_amdgcn_mfma_f32_16x16x32_bf16(
              af[m], bf[nn], acc[m][nn], 0, 0, 0);
    }
  }
#pragma unroll
  for (int m = 0; m < 4; ++m)
#pragma unroll
    for (int nn = 0; nn < 4; ++nn)
#pragma unroll
      for (int rg = 0; rg < 4; ++rg) {
        const int row = m0 + wr * 64 + m * 16 + 4 * g + rg;
        const int col = nb * 128 + wc * 64 + nn * 16 + c;
        C[(size_t)row * DM + col] = f2bf(acc[m][nn][rg]);
      }
}

// ---------------------------------------------------------------------------
// out[4096][512] = Ah*Bh^T + Al*Bh^T + Ah*Bl^T   (split-bf16, f32 accum)
// A = attention output (hi/lo), B = Wo rows (hi/lo), both k-contiguous.
// ---------------------------------------------------------------------------
__global__ __launch_bounds__(256) void k_out_mfma(
    const unsigned short* __restrict__ Ah, const unsigned short* __restrict__ Al,
    const unsigned short* __restrict__ Bh, const unsigned short* __restrict__ Bl,
    float* __restrict__ C) {
  __shared__ unsigned short bufAh[64 * 64], bufAl[64 * 64];
  __shared__ unsigned short bufBh[64 * 64], bufBl[64 * 64];
  const int tid = threadIdx.x, w = tid >> 6, lane = tid & 63;
  const int c = lane & 15, g = lane >> 4;
  const int wr = w >> 1, wc = w & 1;
  const int bm = blockIdx.x, bn = blockIdx.y;
  const int lrow = lane >> 3, lslot = lane & 7;
  floatx4 acc[2][2];
#pragma unroll
  for (int mi = 0; mi < 2; ++mi)
#pragma unroll
    for (int ni = 0; ni < 2; ++ni) acc[mi][ni] = (floatx4){0.f, 0.f, 0.f, 0.f};

  for (int k0 = 0; k0 < DM; k0 += 64) {
    __syncthreads();
#pragma unroll
    for (int iq = 0; iq < 2; ++iq) {
      const int r0 = w * 16 + iq * 8;
      const int arow = r0 + lrow;
      const int sg = lslot ^ (arow & 7);
      GLOAD_LDS16(Ah + (size_t)(bm * 64 + arow) * DM + k0 + sg * 8, bufAh + r0 * 64);
      GLOAD_LDS16(Al + (size_t)(bm * 64 + arow) * DM + k0 + sg * 8, bufAl + r0 * 64);
      GLOAD_LDS16(Bh + (size_t)(bn * 64 + arow) * DM + k0 + sg * 8, bufBh + r0 * 64);
      GLOAD_LDS16(Bl + (size_t)(bn * 64 + arow) * DM + k0 + sg * 8, bufBl + r0 * 64);
    }
    __syncthreads();
#pragma unroll
    for (int kk = 0; kk < 2; ++kk) {
      short8 ah[2], al[2], bh[2], bl[2];
#pragma unroll
      for (int mi = 0; mi < 2; ++mi) {
        const int row = wr * 32 + mi * 16 + c;
        const int slot = (kk * 4 + g) ^ (row & 7);
        ah[mi] = *(const short8*)(bufAh + row * 64 + slot * 8);
        al[mi] = *(const short8*)(bufAl + row * 64 + slot * 8);
      }
#pragma unroll
      for (int ni = 0; ni < 2; ++ni) {
        const int row = wc * 32 + ni * 16 + c;
        const int slot = (kk * 4 + g) ^ (row & 7);
        bh[ni] = *(const short8*)(bufBh + row * 64 + slot * 8);
        bl[ni] = *(const short8*)(bufBl + row * 64 + slot * 8);
      }
#pragma unroll
      for (int mi = 0; mi < 2; ++mi)
#pragma unroll
        for (int ni = 0; ni < 2; ++ni) {
          acc[mi][ni] = __builtin_amdgcn_mfma_f32_16x16x32_bf16(
              ah[mi], bh[ni], acc[mi][ni], 0, 0, 0);
          acc[mi][ni] = __builtin_amdgcn_mfma_f32_16x16x32_bf16(
              al[mi], bh[ni], acc[mi][ni], 0, 0, 0);
          acc[mi][ni] = __builtin_amdgcn_mfma_f32_16x16x32_bf16(
              ah[mi], bl[ni], acc[mi][ni], 0, 0, 0);
        }
    }
  }
#pragma unroll
  for (int mi = 0; mi < 2; ++mi)
#pragma unroll
    for (int ni = 0; ni < 2; ++ni)
#pragma unroll
      for (int rg = 0; rg < 4; ++rg) {
        const int row = bm * 64 + wr * 32 + mi * 16 + 4 * g + rg;
        const int col = bn * 64 + wc * 32 + ni * 16 + c;
        C[(size_t)row * DM + col] = acc[mi][ni][rg];
      }
}

// ---------------------------------------------------------------------------
// Flash MFMA attention, intra-block split-K: 8 waves (512 thr); wave w:
// qsub = w&3 (16 q rows), half = w>>2 (even/odd key tiles). Merge via LDS.
// score(i,j) = qk_i.k_j + qr_i.r[j-i+1023], valid j <= i+1024.
// BD diagonal gather done with register shuffles (src lane = same g, rotated c).
// ---------------------------------------------------------------------------
__global__ __launch_bounds__(512, 4) void k_attn_mfma(
    const unsigned short* __restrict__ q, const unsigned short* __restrict__ k,
    const unsigned short* __restrict__ v, const unsigned short* __restrict__ r,
    const float* __restrict__ bk, const float* __restrict__ br,
    unsigned short* __restrict__ aoh, unsigned short* __restrict__ aol) {
  __shared__ unsigned short VT[2][64][74];   // per-half V^T tile
  __shared__ char smix[19968];               // P (in-loop) / combine (post-loop)
  unsigned short (*P)[16][76] = (unsigned short (*)[16][76])smix;  // [8 waves]
  float (*oC)[16][68] = (float (*)[16][68])smix;                   // [4 qsub]
  float* mlC = (float*)(smix + 17408);                             // [4][2][16]

  const int tid = threadIdx.x;
  const int w = tid >> 6;
  const int half = w >> 2;
  const int qsub = w & 3;
  const int lane = tid & 63;
  const int c = lane & 15;
  const int g = lane >> 4;
  const int n = blockIdx.y;
  const int b = blockIdx.z;
  const int grp = (n + NHEAD * b) >> 4;   // z>=2 reversed: co-resident pair balance
  const int i0 = (grp ? (15 - (int)blockIdx.x) : (int)blockIdx.x) * 64;
  const int qb = i0 + qsub * 16;

  short8 aqk[2], aqr[2];
  {
    const unsigned short* qrow =
        q + ((size_t)(b * QLEN) + qb + c) * DM + n * DHEAD;
#pragma unroll
    for (int kb2 = 0; kb2 < 2; ++kb2) {
      short8 qv = *(const short8*)(qrow + kb2 * 32 + g * 8);
#pragma unroll
      for (int j = 0; j < 8; ++j) {
        int d = kb2 * 32 + g * 8 + j;
        float f = bf2f((unsigned short)qv[j]);
        aqk[kb2][j] = (short)f2bf((f + bk[n * DHEAD + d]) * 0.125f);
        aqr[kb2][j] = (short)f2bf((f + br[n * DHEAD + d]) * 0.125f);
      }
    }
  }

  floatx4 o[4];
#pragma unroll
  for (int t = 0; t < 4; ++t) o[t] = (floatx4){0.f, 0.f, 0.f, 0.f};
  float m[4], lsum[4];
#pragma unroll
  for (int rg = 0; rg < 4; ++rg) { m[rg] = -1e30f; lsum[rg] = 0.f; }

  const int nkb = i0 / 64 + 17;
  const int nit = (nkb + 1) >> 1;
  const int tidh = tid & 255;
  const int key0 = tidh >> 3, d0 = (tidh & 7) * 8;

  short8 vcur[2];
  {
    const int jv = half * 64;
    vcur[0] = *(const short8*)(v + ((size_t)(b * KLEN) + jv + key0) * DM + n * DHEAD + d0);
    vcur[1] = *(const short8*)(v + ((size_t)(b * KLEN) + jv + key0 + 32) * DM + n * DHEAD + d0);
  }

  for (int it = 0; it < nit; ++it) {
    const int t = half + 2 * it;
    const bool active = (t < nkb);
    const int j0 = t * 64;
    __syncthreads();
    if (active) {
#pragma unroll
      for (int rep = 0; rep < 2; ++rep)
#pragma unroll
        for (int j = 0; j < 8; ++j)
          VT[half][d0 + j][key0 + rep * 32] = (unsigned short)vcur[rep][j];
    }
    short8 vnext[2];
    const bool pf = (t + 2 < nkb);
    if (pf) {
      vnext[0] = *(const short8*)(
          v + ((size_t)(b * KLEN) + j0 + 128 + key0) * DM + n * DHEAD + d0);
      vnext[1] = *(const short8*)(
          v + ((size_t)(b * KLEN) + j0 + 160 + key0) * DM + n * DHEAD + d0);
    }
    __syncthreads();
    if (active) {
      // BD tiles in regs + shuffle into gathered form
      const int jrbase = j0 - qb + 1008;
      float sh[5][4];
#pragma unroll
      for (int tau5 = 0; tau5 < 5; ++tau5) {
        const int jrow = min(jrbase + tau5 * 16 + c, KLEN - 1);
        const unsigned short* rr = r + (size_t)jrow * DM + n * DHEAD;
        short8 rf0 = *(const short8*)(rr + g * 8);
        short8 rf1 = *(const short8*)(rr + 32 + g * 8);
        floatx4 bd = (floatx4){0.f, 0.f, 0.f, 0.f};
        bd = __builtin_amdgcn_mfma_f32_16x16x32_bf16(aqr[0], rf0, bd, 0, 0, 0);
        bd = __builtin_amdgcn_mfma_f32_16x16x32_bf16(aqr[1], rf1, bd, 0, 0, 0);
#pragma unroll
        for (int rg = 0; rg < 4; ++rg) {
          const int srcl = (g << 4) | ((15 + c - 4 * g - rg) & 15);
          sh[tau5][rg] = __shfl(bd[rg], srcl, 64);
        }
      }

      // AC + gather + mask
      floatx4 s[4];
      const bool lastblk = (t == nkb - 1);
#pragma unroll
      for (int tau = 0; tau < 4; ++tau) {
        const unsigned short* kr =
            k + ((size_t)(b * KLEN) + j0 + tau * 16 + c) * DM + n * DHEAD;
        short8 kf0 = *(const short8*)(kr + g * 8);
        short8 kf1 = *(const short8*)(kr + 32 + g * 8);
        floatx4 acc = (floatx4){0.f, 0.f, 0.f, 0.f};
        acc = __builtin_amdgcn_mfma_f32_16x16x32_bf16(aqk[0], kf0, acc, 0, 0, 0);
        acc = __builtin_amdgcn_mfma_f32_16x16x32_bf16(aqk[1], kf1, acc, 0, 0, 0);
#pragma unroll
        for (int rg = 0; rg < 4; ++rg) {
          const int ql = 4 * g + rg;
          float sv = acc[rg] + ((c > ql) ? sh[tau + 1][rg] : sh[tau][rg]);
          if (lastblk && (tau * 16 + c > qsub * 16 + ql)) sv = -1e30f;
          s[tau][rg] = sv;
        }
      }

      // online softmax
      float fac[4];
#pragma unroll
      for (int rg = 0; rg < 4; ++rg) {
        float mx = fmaxf(fmaxf(s[0][rg], s[1][rg]), fmaxf(s[2][rg], s[3][rg]));
#pragma unroll
        for (int shm = 1; shm < 16; shm <<= 1) mx = fmaxf(mx, __shfl_xor(mx, shm, 64));
        float mn = fmaxf(m[rg], mx);
        fac[rg] = __expf(m[rg] - mn);
        m[rg] = mn;
      }
      float rsum[4] = {0.f, 0.f, 0.f, 0.f};
#pragma unroll
      for (int tau = 0; tau < 4; ++tau) {
#pragma unroll
        for (int rg = 0; rg < 4; ++rg) {
          float p = __expf(s[tau][rg] - m[rg]);
          rsum[rg] += p;
          P[w][4 * g + rg][tau * 16 + c] = f2bf(p);
        }
      }
#pragma unroll
      for (int rg = 0; rg < 4; ++rg) {
        float rs = rsum[rg];
#pragma unroll
        for (int shm = 1; shm < 16; shm <<= 1) rs += __shfl_xor(rs, shm, 64);
        lsum[rg] = lsum[rg] * fac[rg] + rs;
#pragma unroll
        for (int td = 0; td < 4; ++td) o[td][rg] *= fac[rg];
      }

      // PV
      short8 pa0 = *(const short8*)&P[w][c][g * 8];
      short8 pa1 = *(const short8*)&P[w][c][32 + g * 8];
#pragma unroll
      for (int td = 0; td < 4; ++td) {
        short8 vb0 = *(const short8*)&VT[half][td * 16 + c][g * 8];
        short8 vb1 = *(const short8*)&VT[half][td * 16 + c][32 + g * 8];
        o[td] = __builtin_amdgcn_mfma_f32_16x16x32_bf16(pa0, vb0, o[td], 0, 0, 0);
        o[td] = __builtin_amdgcn_mfma_f32_16x16x32_bf16(pa1, vb1, o[td], 0, 0, 0);
      }
    }
    if (pf) { vcur[0] = vnext[0]; vcur[1] = vnext[1]; }
  }

  // combine halves
  __syncthreads();
  if (half == 1) {
#pragma unroll
    for (int td = 0; td < 4; ++td)
#pragma unroll
      for (int rg = 0; rg < 4; ++rg)
        oC[qsub][4 * g + rg][td * 16 + c] = o[td][rg];
    if (c == 0) {
#pragma unroll
      for (int rg = 0; rg < 4; ++rg) {
        mlC[(qsub * 2 + 0) * 16 + 4 * g + rg] = m[rg];
        mlC[(qsub * 2 + 1) * 16 + 4 * g + rg] = lsum[rg];
      }
    }
  }
  __syncthreads();
  if (half == 0) {
#pragma unroll
    for (int rg = 0; rg < 4; ++rg) {
      const int ql = 4 * g + rg;
      float m1 = mlC[(qsub * 2 + 0) * 16 + ql];
      float l1 = mlC[(qsub * 2 + 1) * 16 + ql];
      float M = fmaxf(m[rg], m1);
      float w0 = __expf(m[rg] - M);
      float w1 = __expf(m1 - M);
      float invl = 1.0f / (lsum[rg] * w0 + l1 * w1);
#pragma unroll
      for (int td = 0; td < 4; ++td) {
        float val = (o[td][rg] * w0 + oC[qsub][ql][td * 16 + c] * w1) * invl;
        unsigned short hi = f2bf(val);
        float lo = val - bf2f(hi);
        size_t off = ((size_t)(b * QLEN) + qb + ql) * DM + n * DHEAD + td * 16 + c;
        aoh[off] = hi;
        aol[off] = f2bf(lo);
      }
    }
  }
}

// ---------------------------------------------------------------------------
extern "C" void kernel_launch(void* const* d_in, const int* in_sizes, int n_in,
                              void* d_out, int out_size, void* d_ws, size_t ws_size,
                              hipStream_t stream) {
  const float* x  = (const float*)d_in[0];
  const float* p  = (const float*)d_in[1];
  const float* Wq = (const float*)d_in[2];
  const float* Wk = (const float*)d_in[3];
  const float* Wv = (const float*)d_in[4];
  const float* Wo = (const float*)d_in[5];
  const float* Wp = (const float*)d_in[6];
  const float* bk = (const float*)d_in[7];
  const float* br = (const float*)d_in[8];
  float* out = (float*)d_out;

  unsigned short* q_  = (unsigned short*)d_ws;        // 2M u16
  unsigned short* k_  = q_  + (size_t)2097152;        // 4M
  unsigned short* v_  = k_  + (size_t)4194304;        // 4M
  unsigned short* r_  = v_  + (size_t)4194304;        // 1M
  unsigned short* xb  = r_  + (size_t)1048576;        // 4M
  unsigned short* pb  = xb  + (size_t)4194304;        // 1M
  unsigned short* wt  = pb  + (size_t)1048576;        // 1M
  unsigned short* woh = wt  + (size_t)1048576;        // 256K
  unsigned short* wol = woh + (size_t)262144;         // 256K
  unsigned short* aoh = wol + (size_t)262144;         // 2M
  unsigned short* aol = aoh + (size_t)2097152;        // 2M

  k_f32bf16<<<2048, 256, 0, stream>>>(x, xb, (B_SZ * KLEN * DM) / 8);
  k_f32bf16<<<512, 256, 0, stream>>>(p, pb, (KLEN * DM) / 8);
  k_wtrans<<<dim3(8, 8, 4), 256, 0, stream>>>(Wq, Wk, Wv, Wp, wt);
  k_wosplit<<<128, 256, 0, stream>>>(Wo, woh, wol, (DM * DM) / 8);
  k_proj_mfma<<<dim3(176, 4), 256, 0, stream>>>(xb, pb, wt, q_, k_, v_, r_);
  k_attn_mfma<<<dim3(16, 8, 4), 512, 0, stream>>>(
      q_, k_, v_, r_, bk, br, aoh, aol);
  k_out_mfma<<<dim3(64, 8), 256, 0, stream>>>(aoh, aol, woh, wol, out);
}